// Round 2
// baseline (233.272 us; speedup 1.0000x reference)
//
#include <hip/hip_runtime.h>

#define NN 512

typedef __attribute__((ext_vector_type(8))) short bf16x8;
typedef __attribute__((ext_vector_type(4))) float f32x4;

__device__ __forceinline__ unsigned short f2bf(float x) {
    union { float f; unsigned u; } c; c.f = x;
    unsigned u = c.u + 0x7fffu + ((c.u >> 16) & 1u);
    return (unsigned short)(u >> 16);
}

__device__ __forceinline__ int find_bin(float d) {
    int bin = 22;  // 22 = "no bin" (zero row in WdT/WscT)
    #pragma unroll
    for (int k = 0; k < 22; ++k) {
        float lo = (float)(1e-3 + k * ((20.0 - 1e-3) / 21.0));
        float hi = (k < 21) ? (float)(1e-3 + (k + 1) * ((20.0 - 1e-3) / 21.0)) : 1e8f;
        if (d > lo && d < hi) bin = k;
    }
    return bin;
}

// ---- fused prep: W1-column gathers, W2/W3 MFMA-fragment packs, relpos table,
//      p_i node embed, and the per-pair distogram bin table ----
__global__ __launch_bounds__(128) void k_prep(
        const float* __restrict__ s, const float* __restrict__ t,
        const float* __restrict__ sct,
        const float* __restrict__ Wsp, const float* __restrict__ bsp,
        const float* __restrict__ Wrp, const float* __restrict__ brp,
        const float* __restrict__ W1, const float* __restrict__ b1,
        const float* __restrict__ W2, const float* __restrict__ W3,
        float* __restrict__ p_i, float* __restrict__ relT,
        float* __restrict__ WdT, float* __restrict__ WscT,
        unsigned short* __restrict__ w2a, unsigned short* __restrict__ w3a,
        unsigned short* __restrict__ binT)
{
    __shared__ float sh[2][256];
    const int blk = blockIdx.x, tid = threadIdx.x;

    if (blk < 23) {
        // W1 distogram column gathers (row 22 = zeros)
        const int bin = blk, c = tid;
        WdT[bin * 128 + c]  = (bin < 22) ? W1[c * 236 + 192 + bin] : 0.0f;
        WscT[bin * 128 + c] = (bin < 22) ? W1[c * 236 + 214 + bin] : 0.0f;
    } else if (blk < 55) {
        // pack W2/W3 (128x128) into MFMA fragment order, bf16.
        // entry idx holds W[ct*16 + (lane&15)][ks*32 + (lane>>4)*8 + e]
        const int seg = blk - 23;           // 0..31
        const int isW3 = seg >> 4;
        const int idx = (seg & 15) * 128 + tid;   // 0..2047
        const int lane = idx & 63, ks = (idx >> 6) & 3, ct = idx >> 8;
        const float* W = isW3 ? W3 : W2;
        unsigned short* dst = isW3 ? w3a : w2a;
        const float* wp = W + (ct * 16 + (lane & 15)) * 128 + ks * 32 + (lane >> 4) * 8;
        unsigned r0 = (unsigned)f2bf(wp[0]) | ((unsigned)f2bf(wp[1]) << 16);
        unsigned r1 = (unsigned)f2bf(wp[2]) | ((unsigned)f2bf(wp[3]) << 16);
        unsigned r2 = (unsigned)f2bf(wp[4]) | ((unsigned)f2bf(wp[5]) << 16);
        unsigned r3 = (unsigned)f2bf(wp[6]) | ((unsigned)f2bf(wp[7]) << 16);
        uint4 v = { r0, r1, r2, r3 };
        *(uint4*)(dst + idx * 8) = v;
    } else if (blk < 1078) {
        // relT[d] = (pos_emb(d) @ W_rp^T + b_rp) @ W1[:,128:192]^T + b1
        const int row = blk - 55;           // 0..1022
        const float d = (float)(row - 511);
        if (tid < 32) {
            float f = powf(2056.0f, (float)tid * (1.0f / 32.0f));
            float ang = d * 3.14159265358979323846f / f;
            sh[0][tid] = sinf(ang);
            sh[0][tid + 32] = cosf(ang);
        }
        __syncthreads();
        if (tid < 64) {
            const float* wr = Wrp + tid * 64;
            float a = brp[tid];
            #pragma unroll
            for (int k = 0; k < 64; ++k) a += sh[0][k] * wr[k];
            sh[1][tid] = a;
        }
        __syncthreads();
        const float* w = W1 + tid * 236 + 128;
        float a = b1[tid];
        #pragma unroll
        for (int k = 0; k < 64; ++k) a += sh[1][k] * w[k];
        relT[row * 128 + tid] = a;
    } else if (blk < 1590) {
        // p_i = s @ Wsp^T + bsp, two rows per block
        const int half = tid >> 6, ch = tid & 63;
        const int row = (blk - 1078) * 2 + half;
        *(float4*)&sh[half][ch * 4] = *(const float4*)&s[row * 256 + ch * 4];
        __syncthreads();
        const float* w = Wsp + ch * 256;
        float acc = bsp[ch];
        #pragma unroll 8
        for (int k = 0; k < 256; k += 4)
            acc += sh[half][k]*w[k] + sh[half][k+1]*w[k+1] + sh[half][k+2]*w[k+2] + sh[half][k+3]*w[k+3];
        p_i[row * 64 + ch] = acc;
    } else {
        // distogram bins for every (bi, j) pair, packed
        const int pair = (blk - 1590) * 128 + tid;   // 0..524287
        const int bi = pair >> 9, j = pair & (NN - 1);
        const int rj = (bi & ~(NN - 1)) + j;
        float ax = t[bi*3+0] - t[rj*3+0];
        float ay = t[bi*3+1] - t[rj*3+1];
        float az = t[bi*3+2] - t[rj*3+2];
        int bD = find_bin(sqrtf(ax*ax + ay*ay + az*az));
        float sx = sct[bi*3+0] - sct[rj*3+0];
        float sy = sct[bi*3+1] - sct[rj*3+1];
        float sz = sct[bi*3+2] - sct[rj*3+2];
        int bS = find_bin(sqrtf(sx*sx + sy*sy + sz*sz));
        binT[pair] = (unsigned short)(bD | (bS << 5));
    }
}

// ---- qL/qR: per-node contributions through W1 cols [0:64) and [64:128) ----
__global__ __launch_bounds__(128) void k_ql(const float* __restrict__ p_i,
        const float* __restrict__ W1, float* __restrict__ qL, float* __restrict__ qR)
{
    __shared__ float pr[64];
    const int row = blockIdx.x, tid = threadIdx.x;
    if (tid < 16) *(float4*)&pr[tid * 4] = *(const float4*)&p_i[row * 64 + tid * 4];
    __syncthreads();
    const float* w = W1 + tid * 236;
    float aL = 0.f, aR = 0.f;
    #pragma unroll
    for (int k = 0; k < 64; ++k) { aL += pr[k] * w[k]; aR += pr[k] * w[64 + k]; }
    qL[row * 128 + tid] = aL;
    qR[row * 128 + tid] = aR;
}

// ---- main fused kernel: barrier-free, wave-local; 1 wave = 16 rows of j ----
__global__ __launch_bounds__(256) void k_main(
    const float* __restrict__ pmask,
    const float* __restrict__ qL, const float* __restrict__ qR,
    const float* __restrict__ relT, const float* __restrict__ WdT,
    const float* __restrict__ WscT, const unsigned short* __restrict__ binT,
    const unsigned short* __restrict__ w2a, const unsigned short* __restrict__ w3a,
    const float* __restrict__ b2, const float* __restrict__ b3,
    const float* __restrict__ lng, const float* __restrict__ lnb,
    float* __restrict__ out)
{
    __shared__ char h2buf[4][4096];   // per-wave 16 rows x 256B, XOR-swizzled

    const int tid  = threadIdx.x;
    const int w    = tid >> 6;
    const int l    = tid & 63;
    const int jloc = l & 15;
    const int gq   = l >> 4;

    const int blk   = blockIdx.x;
    const int bi    = blk >> 3;               // b*512 + i
    const int i     = bi & (NN - 1);
    const int bbase = bi & ~(NN - 1);
    const int j     = (blk & 7) * 64 + w * 16 + jloc;

    const unsigned bv = binT[bi * NN + j];
    const int binD = bv & 31, binSC = (int)(bv >> 5);
    const float mask = pmask[(size_t)bi * NN + j];

    const float* qLp = qL + bi * 128;
    const float* qRp = qR + (bbase + j) * 128;
    const float* rTp = relT + (i - j + NN - 1) * 128;
    const float* dTp = WdT + binD * 128;
    const float* sTp = WscT + binSC * 128;

    // ---- h1 = relu(qL + qR + relT + WdT[bin] + WscT[bin]) as B-fragments in regs ----
    bf16x8 bfr[4];
    #pragma unroll
    for (int ks = 0; ks < 4; ++ks) {
        const int c0 = ks * 32 + gq * 8;
        float x[8];
        #pragma unroll
        for (int h = 0; h < 2; ++h) {
            const int c = c0 + h * 4;
            float4 v0 = *(const float4*)(qLp + c);
            float4 v1 = *(const float4*)(qRp + c);
            float4 v2 = *(const float4*)(rTp + c);
            float4 v3 = *(const float4*)(dTp + c);
            float4 v4 = *(const float4*)(sTp + c);
            x[h*4+0] = fmaxf(v0.x + v1.x + v2.x + v3.x + v4.x, 0.0f);
            x[h*4+1] = fmaxf(v0.y + v1.y + v2.y + v3.y + v4.y, 0.0f);
            x[h*4+2] = fmaxf(v0.z + v1.z + v2.z + v3.z + v4.z, 0.0f);
            x[h*4+3] = fmaxf(v0.w + v1.w + v2.w + v3.w + v4.w, 0.0f);
        }
        bf16x8 r;
        #pragma unroll
        for (int e = 0; e < 8; ++e) r[e] = (short)f2bf(x[e]);
        bfr[ks] = r;
    }

    // ---- GEMM2: A = W2 fragments (global, L1-hot), B = h1; D rows = channels ----
    const bf16x8* w2p = (const bf16x8*)w2a;
    f32x4 acc2[8];
    #pragma unroll
    for (int ct = 0; ct < 8; ++ct) {
        f32x4 c4 = {0.f, 0.f, 0.f, 0.f};
        #pragma unroll
        for (int ks = 0; ks < 4; ++ks)
            c4 = __builtin_amdgcn_mfma_f32_16x16x32_bf16(w2p[ct*256 + ks*64 + l], bfr[ks], c4, 0, 0, 0);
        acc2[ct] = c4;
    }

    // ---- h2 = relu(acc2 + b2): each lane owns 4 consecutive channels -> ds_write_b64 ----
    char* hb = h2buf[w];
    const int rswz = (jloc & 7) << 4;
    #pragma unroll
    for (int ct = 0; ct < 8; ++ct) {
        const int c = ct * 16 + gq * 4;
        float4 bb = *(const float4*)(b2 + c);
        float y0 = fmaxf(acc2[ct][0] + bb.x, 0.0f);
        float y1 = fmaxf(acc2[ct][1] + bb.y, 0.0f);
        float y2 = fmaxf(acc2[ct][2] + bb.z, 0.0f);
        float y3 = fmaxf(acc2[ct][3] + bb.w, 0.0f);
        uint2 pk;
        pk.x = (unsigned)f2bf(y0) | ((unsigned)f2bf(y1) << 16);
        pk.y = (unsigned)f2bf(y2) | ((unsigned)f2bf(y3) << 16);
        *(uint2*)(hb + ((jloc * 256 + c * 2) ^ rswz)) = pk;
    }

    // ---- read back as GEMM3 B-fragments (wave-local: lgkmcnt wait, no barrier) ----
    bf16x8 b3f[4];
    #pragma unroll
    for (int ks = 0; ks < 4; ++ks)
        b3f[ks] = *(bf16x8*)(hb + ((jloc * 256 + ks * 64 + gq * 16) ^ rswz));

    // ---- GEMM3 ----
    const bf16x8* w3p = (const bf16x8*)w3a;
    f32x4 acc3[8];
    #pragma unroll
    for (int ct = 0; ct < 8; ++ct) {
        f32x4 c4 = {0.f, 0.f, 0.f, 0.f};
        #pragma unroll
        for (int ks = 0; ks < 4; ++ks)
            c4 = __builtin_amdgcn_mfma_f32_16x16x32_bf16(w3p[ct*256 + ks*64 + l], b3f[ks], c4, 0, 0, 0);
        acc3[ct] = c4;
    }

    // ---- + b3, LayerNorm (2 shuffles across the 4 gq lanes), scale, mask, store f4 ----
    float s1 = 0.f, s2 = 0.f;
    #pragma unroll
    for (int ct = 0; ct < 8; ++ct) {
        const int c = ct * 16 + gq * 4;
        float4 bb = *(const float4*)(b3 + c);
        acc3[ct][0] += bb.x; acc3[ct][1] += bb.y;
        acc3[ct][2] += bb.z; acc3[ct][3] += bb.w;
        #pragma unroll
        for (int r = 0; r < 4; ++r) { float v = acc3[ct][r]; s1 += v; s2 += v * v; }
    }
    s1 += __shfl_xor(s1, 16); s2 += __shfl_xor(s2, 16);
    s1 += __shfl_xor(s1, 32); s2 += __shfl_xor(s2, 32);
    const float mean = s1 * (1.0f / 128.0f);
    const float var  = s2 * (1.0f / 128.0f) - mean * mean;
    const float rstd = rsqrtf(var + 1e-5f);

    float* op = out + ((size_t)(bi * NN + j)) * 128;
    #pragma unroll
    for (int ct = 0; ct < 8; ++ct) {
        const int c = ct * 16 + gq * 4;
        float4 g4 = *(const float4*)(lng + c);
        float4 be = *(const float4*)(lnb + c);
        float4 o;
        o.x = ((acc3[ct][0] - mean) * rstd * g4.x + be.x) * mask;
        o.y = ((acc3[ct][1] - mean) * rstd * g4.y + be.y) * mask;
        o.z = ((acc3[ct][2] - mean) * rstd * g4.z + be.z) * mask;
        o.w = ((acc3[ct][3] - mean) * rstd * g4.w + be.w) * mask;
        *(float4*)(op + c) = o;
    }
}

extern "C" void kernel_launch(void* const* d_in, const int* in_sizes, int n_in,
                              void* d_out, int out_size, void* d_ws, size_t ws_size,
                              hipStream_t stream)
{
    const float* s   = (const float*)d_in[0];
    const float* t   = (const float*)d_in[1];
    const float* sct = (const float*)d_in[2];
    const float* pm  = (const float*)d_in[3];
    const float* Wsp = (const float*)d_in[4];
    const float* bsp = (const float*)d_in[5];
    const float* Wrp = (const float*)d_in[6];
    const float* brp = (const float*)d_in[7];
    const float* W1  = (const float*)d_in[8];
    const float* b1  = (const float*)d_in[9];
    const float* W2  = (const float*)d_in[10];
    const float* b2  = (const float*)d_in[11];
    const float* W3  = (const float*)d_in[12];
    const float* b3  = (const float*)d_in[13];
    const float* lng = (const float*)d_in[14];
    const float* lnb = (const float*)d_in[15];

    float* ws   = (float*)d_ws;
    float* p_i  = ws;                                    // 65536
    float* qL   = ws + 65536;                            // 131072
    float* qR   = ws + 196608;                           // 131072
    float* relT = ws + 327680;                           // 130944
    float* WdT  = ws + 458624;                           // 2944
    float* WscT = ws + 461568;                           // 2944
    unsigned short* w2a  = (unsigned short*)(ws + 464512);   // 16384 u16
    unsigned short* w3a  = (unsigned short*)(ws + 472704);   // 16384 u16
    unsigned short* binT = (unsigned short*)(ws + 480896);   // 524288 u16

    k_prep<<<5686, 128, 0, stream>>>(s, t, sct, Wsp, bsp, Wrp, brp, W1, b1, W2, W3,
                                     p_i, relT, WdT, WscT, w2a, w3a, binT);
    k_ql<<<1024, 128, 0, stream>>>(p_i, W1, qL, qR);
    k_main<<<8192, 256, 0, stream>>>(pm, qL, qR, relT, WdT, WscT, binT,
                                     w2a, w3a, b2, b3, lng, lnb, (float*)d_out);
}

// Round 3
// 229.193 us; speedup vs baseline: 1.0178x; 1.0178x over previous
//
#include <hip/hip_runtime.h>

#define NN 512

typedef __attribute__((ext_vector_type(8))) short bf16x8;
typedef __attribute__((ext_vector_type(4))) float f32x4;

__device__ __forceinline__ unsigned short f2bf(float x) {
    union { float f; unsigned u; } c; c.f = x;
    unsigned u = c.u + 0x7fffu + ((c.u >> 16) & 1u);
    return (unsigned short)(u >> 16);
}

__device__ __forceinline__ int find_bin(float d) {
    int bin = 22;  // 22 = "no bin" (zero row in WdT/WscT)
    #pragma unroll
    for (int k = 0; k < 22; ++k) {
        float lo = (float)(1e-3 + k * ((20.0 - 1e-3) / 21.0));
        float hi = (k < 21) ? (float)(1e-3 + (k + 1) * ((20.0 - 1e-3) / 21.0)) : 1e8f;
        if (d > lo && d < hi) bin = k;
    }
    return bin;
}

// ---- fused prep: W1-column gathers, W2/W3 MFMA-fragment packs, relpos table,
//      p_i node embed, and the per-pair distogram bin table ----
__global__ __launch_bounds__(128) void k_prep(
        const float* __restrict__ s, const float* __restrict__ t,
        const float* __restrict__ sct,
        const float* __restrict__ Wsp, const float* __restrict__ bsp,
        const float* __restrict__ Wrp, const float* __restrict__ brp,
        const float* __restrict__ W1, const float* __restrict__ b1,
        const float* __restrict__ W2, const float* __restrict__ W3,
        float* __restrict__ p_i, float* __restrict__ relT,
        float* __restrict__ WdT, float* __restrict__ WscT,
        unsigned short* __restrict__ w2a, unsigned short* __restrict__ w3a,
        unsigned short* __restrict__ binT)
{
    __shared__ float sh[2][256];
    const int blk = blockIdx.x, tid = threadIdx.x;

    if (blk < 23) {
        // W1 distogram column gathers (row 22 = zeros)
        const int bin = blk, c = tid;
        WdT[bin * 128 + c]  = (bin < 22) ? W1[c * 236 + 192 + bin] : 0.0f;
        WscT[bin * 128 + c] = (bin < 22) ? W1[c * 236 + 214 + bin] : 0.0f;
    } else if (blk < 55) {
        // pack W2/W3 (128x128) into MFMA fragment order, bf16.
        // entry idx holds W[ct*16 + (lane&15)][ks*32 + (lane>>4)*8 + e]
        const int seg = blk - 23;           // 0..31
        const int isW3 = seg >> 4;
        const int idx = (seg & 15) * 128 + tid;   // 0..2047
        const int lane = idx & 63, ks = (idx >> 6) & 3, ct = idx >> 8;
        const float* W = isW3 ? W3 : W2;
        unsigned short* dst = isW3 ? w3a : w2a;
        const float* wp = W + (ct * 16 + (lane & 15)) * 128 + ks * 32 + (lane >> 4) * 8;
        unsigned r0 = (unsigned)f2bf(wp[0]) | ((unsigned)f2bf(wp[1]) << 16);
        unsigned r1 = (unsigned)f2bf(wp[2]) | ((unsigned)f2bf(wp[3]) << 16);
        unsigned r2 = (unsigned)f2bf(wp[4]) | ((unsigned)f2bf(wp[5]) << 16);
        unsigned r3 = (unsigned)f2bf(wp[6]) | ((unsigned)f2bf(wp[7]) << 16);
        uint4 v = { r0, r1, r2, r3 };
        *(uint4*)(dst + idx * 8) = v;
    } else if (blk < 1078) {
        // relT[d] = (pos_emb(d) @ W_rp^T + b_rp) @ W1[:,128:192]^T + b1
        const int row = blk - 55;           // 0..1022
        const float d = (float)(row - 511);
        if (tid < 32) {
            float f = powf(2056.0f, (float)tid * (1.0f / 32.0f));
            float ang = d * 3.14159265358979323846f / f;
            sh[0][tid] = sinf(ang);
            sh[0][tid + 32] = cosf(ang);
        }
        __syncthreads();
        if (tid < 64) {
            const float* wr = Wrp + tid * 64;
            float a = brp[tid];
            #pragma unroll
            for (int k = 0; k < 64; ++k) a += sh[0][k] * wr[k];
            sh[1][tid] = a;
        }
        __syncthreads();
        const float* w = W1 + tid * 236 + 128;
        float a = b1[tid];
        #pragma unroll
        for (int k = 0; k < 64; ++k) a += sh[1][k] * w[k];
        relT[row * 128 + tid] = a;
    } else if (blk < 1590) {
        // p_i = s @ Wsp^T + bsp, two rows per block
        const int half = tid >> 6, ch = tid & 63;
        const int row = (blk - 1078) * 2 + half;
        *(float4*)&sh[half][ch * 4] = *(const float4*)&s[row * 256 + ch * 4];
        __syncthreads();
        const float* w = Wsp + ch * 256;
        float acc = bsp[ch];
        #pragma unroll 8
        for (int k = 0; k < 256; k += 4)
            acc += sh[half][k]*w[k] + sh[half][k+1]*w[k+1] + sh[half][k+2]*w[k+2] + sh[half][k+3]*w[k+3];
        p_i[row * 64 + ch] = acc;
    } else {
        // distogram bins for every (bi, j) pair, packed
        const int pair = (blk - 1590) * 128 + tid;   // 0..524287
        const int bi = pair >> 9, j = pair & (NN - 1);
        const int rj = (bi & ~(NN - 1)) + j;
        float ax = t[bi*3+0] - t[rj*3+0];
        float ay = t[bi*3+1] - t[rj*3+1];
        float az = t[bi*3+2] - t[rj*3+2];
        int bD = find_bin(sqrtf(ax*ax + ay*ay + az*az));
        float sx = sct[bi*3+0] - sct[rj*3+0];
        float sy = sct[bi*3+1] - sct[rj*3+1];
        float sz = sct[bi*3+2] - sct[rj*3+2];
        int bS = find_bin(sqrtf(sx*sx + sy*sy + sz*sz));
        binT[pair] = (unsigned short)(bD | (bS << 5));
    }
}

// ---- qL/qR: per-node contributions through W1 cols [0:64) and [64:128) ----
__global__ __launch_bounds__(128) void k_ql(const float* __restrict__ p_i,
        const float* __restrict__ W1, float* __restrict__ qL, float* __restrict__ qR)
{
    __shared__ float pr[64];
    const int row = blockIdx.x, tid = threadIdx.x;
    if (tid < 16) *(float4*)&pr[tid * 4] = *(const float4*)&p_i[row * 64 + tid * 4];
    __syncthreads();
    const float* w = W1 + tid * 236;
    float aL = 0.f, aR = 0.f;
    #pragma unroll
    for (int k = 0; k < 64; ++k) { aL += pr[k] * w[k]; aR += pr[k] * w[64 + k]; }
    qL[row * 128 + tid] = aL;
    qR[row * 128 + tid] = aR;
}

// ---- main fused kernel: barrier-free, wave-local; 1 wave = 16 rows of j.
//      Final stores bounced through LDS (rotation swizzle) for 1KB-contiguous
//      wave stores. ----
__global__ __launch_bounds__(256) void k_main(
    const float* __restrict__ pmask,
    const float* __restrict__ qL, const float* __restrict__ qR,
    const float* __restrict__ relT, const float* __restrict__ WdT,
    const float* __restrict__ WscT, const unsigned short* __restrict__ binT,
    const unsigned short* __restrict__ w2a, const unsigned short* __restrict__ w3a,
    const float* __restrict__ b2, const float* __restrict__ b3,
    const float* __restrict__ lng, const float* __restrict__ lnb,
    float* __restrict__ out)
{
    // per-wave 8KB: bytes [0,4096) = h2 (bf16, XOR swizzle); reused (after the
    // wave's GEMM3 B-frag reads) as the 16row x 512B f32 store-stage tile
    // with rotation swizzle. Wave-local -> ordering by lgkmcnt, no barriers.
    __shared__ char wbuf[4][8192];

    const int tid  = threadIdx.x;
    const int w    = tid >> 6;
    const int l    = tid & 63;
    const int jloc = l & 15;
    const int gq   = l >> 4;

    const int blk   = blockIdx.x;
    const int bi    = blk >> 3;               // b*512 + i
    const int i     = bi & (NN - 1);
    const int bbase = bi & ~(NN - 1);
    const int j     = (blk & 7) * 64 + w * 16 + jloc;

    const unsigned bv = binT[bi * NN + j];
    const int binD = bv & 31, binSC = (int)(bv >> 5);
    const float mask = pmask[(size_t)bi * NN + j];

    const float* qLp = qL + bi * 128;
    const float* qRp = qR + (bbase + j) * 128;
    const float* rTp = relT + (i - j + NN - 1) * 128;
    const float* dTp = WdT + binD * 128;
    const float* sTp = WscT + binSC * 128;

    // ---- h1 = relu(qL + qR + relT + WdT[bin] + WscT[bin]) as B-fragments in regs ----
    bf16x8 bfr[4];
    #pragma unroll
    for (int ks = 0; ks < 4; ++ks) {
        const int c0 = ks * 32 + gq * 8;
        float x[8];
        #pragma unroll
        for (int h = 0; h < 2; ++h) {
            const int c = c0 + h * 4;
            float4 v0 = *(const float4*)(qLp + c);
            float4 v1 = *(const float4*)(qRp + c);
            float4 v2 = *(const float4*)(rTp + c);
            float4 v3 = *(const float4*)(dTp + c);
            float4 v4 = *(const float4*)(sTp + c);
            x[h*4+0] = fmaxf(v0.x + v1.x + v2.x + v3.x + v4.x, 0.0f);
            x[h*4+1] = fmaxf(v0.y + v1.y + v2.y + v3.y + v4.y, 0.0f);
            x[h*4+2] = fmaxf(v0.z + v1.z + v2.z + v3.z + v4.z, 0.0f);
            x[h*4+3] = fmaxf(v0.w + v1.w + v2.w + v3.w + v4.w, 0.0f);
        }
        bf16x8 r;
        #pragma unroll
        for (int e = 0; e < 8; ++e) r[e] = (short)f2bf(x[e]);
        bfr[ks] = r;
    }

    // ---- GEMM2: A = W2 fragments (global, L1/L2-hot), B = h1; D rows = channels ----
    const bf16x8* w2p = (const bf16x8*)w2a;
    f32x4 acc2[8];
    #pragma unroll
    for (int ct = 0; ct < 8; ++ct) {
        f32x4 c4 = {0.f, 0.f, 0.f, 0.f};
        #pragma unroll
        for (int ks = 0; ks < 4; ++ks)
            c4 = __builtin_amdgcn_mfma_f32_16x16x32_bf16(w2p[ct*256 + ks*64 + l], bfr[ks], c4, 0, 0, 0);
        acc2[ct] = c4;
    }

    // ---- h2 = relu(acc2 + b2): each lane owns 4 consecutive channels -> ds_write_b64 ----
    char* hb = wbuf[w];
    const int rswz = (jloc & 7) << 4;
    #pragma unroll
    for (int ct = 0; ct < 8; ++ct) {
        const int c = ct * 16 + gq * 4;
        float4 bb = *(const float4*)(b2 + c);
        float y0 = fmaxf(acc2[ct][0] + bb.x, 0.0f);
        float y1 = fmaxf(acc2[ct][1] + bb.y, 0.0f);
        float y2 = fmaxf(acc2[ct][2] + bb.z, 0.0f);
        float y3 = fmaxf(acc2[ct][3] + bb.w, 0.0f);
        uint2 pk;
        pk.x = (unsigned)f2bf(y0) | ((unsigned)f2bf(y1) << 16);
        pk.y = (unsigned)f2bf(y2) | ((unsigned)f2bf(y3) << 16);
        *(uint2*)(hb + ((jloc * 256 + c * 2) ^ rswz)) = pk;
    }

    // ---- read back as GEMM3 B-fragments (wave-local: lgkmcnt wait, no barrier) ----
    bf16x8 b3f[4];
    #pragma unroll
    for (int ks = 0; ks < 4; ++ks)
        b3f[ks] = *(bf16x8*)(hb + ((jloc * 256 + ks * 64 + gq * 16) ^ rswz));

    // ---- GEMM3 ----
    const bf16x8* w3p = (const bf16x8*)w3a;
    f32x4 acc3[8];
    #pragma unroll
    for (int ct = 0; ct < 8; ++ct) {
        f32x4 c4 = {0.f, 0.f, 0.f, 0.f};
        #pragma unroll
        for (int ks = 0; ks < 4; ++ks)
            c4 = __builtin_amdgcn_mfma_f32_16x16x32_bf16(w3p[ct*256 + ks*64 + l], b3f[ks], c4, 0, 0, 0);
        acc3[ct] = c4;
    }

    // ---- + b3, LayerNorm (2 shuffles across the 4 gq lanes) ----
    float s1 = 0.f, s2 = 0.f;
    #pragma unroll
    for (int ct = 0; ct < 8; ++ct) {
        const int c = ct * 16 + gq * 4;
        float4 bb = *(const float4*)(b3 + c);
        acc3[ct][0] += bb.x; acc3[ct][1] += bb.y;
        acc3[ct][2] += bb.z; acc3[ct][3] += bb.w;
        #pragma unroll
        for (int r = 0; r < 4; ++r) { float v = acc3[ct][r]; s1 += v; s2 += v * v; }
    }
    s1 += __shfl_xor(s1, 16); s2 += __shfl_xor(s2, 16);
    s1 += __shfl_xor(s1, 32); s2 += __shfl_xor(s2, 32);
    const float mean = s1 * (1.0f / 128.0f);
    const float var  = s2 * (1.0f / 128.0f) - mean * mean;
    const float rstd = rsqrtf(var + 1e-5f);

    // ---- scale+mask into the rotation-swizzled stage tile (2 lanes/slot = free) ----
    #pragma unroll
    for (int ct = 0; ct < 8; ++ct) {
        const int c = ct * 16 + gq * 4;
        float4 g4 = *(const float4*)(lng + c);
        float4 be = *(const float4*)(lnb + c);
        f32x4 o;
        o[0] = ((acc3[ct][0] - mean) * rstd * g4.x + be.x) * mask;
        o[1] = ((acc3[ct][1] - mean) * rstd * g4.y + be.y) * mask;
        o[2] = ((acc3[ct][2] - mean) * rstd * g4.z + be.z) * mask;
        o[3] = ((acc3[ct][3] - mean) * rstd * g4.w + be.w) * mask;
        const int slot = (ct * 4 + gq + 2 * jloc) & 31;
        *(f32x4*)(hb + jloc * 512 + slot * 16) = o;
    }

    // ---- linear read-back (conflict-free) + 1KB-contiguous nontemporal stores ----
    float* op = out + (((size_t)(bi * NN) + (blk & 7) * 64 + w * 16) * 128);
    #pragma unroll
    for (int it = 0; it < 8; ++it) {
        const int r = it * 2 + (l >> 5);
        const int srd = l & 31;
        const int p = (srd + 2 * r) & 31;
        f32x4 v = *(f32x4*)(hb + r * 512 + p * 16);
        __builtin_nontemporal_store(v, (f32x4*)(op + it * 256 + l * 4));
    }
}

extern "C" void kernel_launch(void* const* d_in, const int* in_sizes, int n_in,
                              void* d_out, int out_size, void* d_ws, size_t ws_size,
                              hipStream_t stream)
{
    const float* s   = (const float*)d_in[0];
    const float* t   = (const float*)d_in[1];
    const float* sct = (const float*)d_in[2];
    const float* pm  = (const float*)d_in[3];
    const float* Wsp = (const float*)d_in[4];
    const float* bsp = (const float*)d_in[5];
    const float* Wrp = (const float*)d_in[6];
    const float* brp = (const float*)d_in[7];
    const float* W1  = (const float*)d_in[8];
    const float* b1  = (const float*)d_in[9];
    const float* W2  = (const float*)d_in[10];
    const float* b2  = (const float*)d_in[11];
    const float* W3  = (const float*)d_in[12];
    const float* b3  = (const float*)d_in[13];
    const float* lng = (const float*)d_in[14];
    const float* lnb = (const float*)d_in[15];

    float* ws   = (float*)d_ws;
    float* p_i  = ws;                                    // 65536
    float* qL   = ws + 65536;                            // 131072
    float* qR   = ws + 196608;                           // 131072
    float* relT = ws + 327680;                           // 130944
    float* WdT  = ws + 458624;                           // 2944
    float* WscT = ws + 461568;                           // 2944
    unsigned short* w2a  = (unsigned short*)(ws + 464512);   // 16384 u16
    unsigned short* w3a  = (unsigned short*)(ws + 472704);   // 16384 u16
    unsigned short* binT = (unsigned short*)(ws + 480896);   // 524288 u16

    k_prep<<<5686, 128, 0, stream>>>(s, t, sct, Wsp, bsp, Wrp, brp, W1, b1, W2, W3,
                                     p_i, relT, WdT, WscT, w2a, w3a, binT);
    k_ql<<<1024, 128, 0, stream>>>(p_i, W1, qL, qR);
    k_main<<<8192, 256, 0, stream>>>(pm, qL, qR, relT, WdT, WscT, binT,
                                     w2a, w3a, b2, b3, lng, lnb, (float*)d_out);
}